// Round 1
// baseline (439.334 us; speedup 1.0000x reference)
//
#include <hip/hip_runtime.h>

#define L2E 1.4426950408889634f

// Sizes (compile-time for this problem; start/current_pos read from device)
#define BB   32      // batch
#define HH   4096    // hidden
#define NH   32      // n heads
#define NKV  8       // n kv heads
#define GG   4       // NH/NKV
#define DD   128     // head dim
#define SWIN 4096    // cache window
#define NQK  6144    // 4096 q cols + 1024 k + 1024 v
#define KSPL 8       // K-split for projections
#define ASPL 16      // sequence splits for attention

__device__ __forceinline__ float xsh(float v, int off) {
    return __shfl_xor(v, off, 64);
}

// ---------------- GEMM core: rows [bq*8, bq*8+8) of x (32xK=4096) times one
// column nloc of W (row-major K x N), K-chunk [k0, k0+512). ----------------
__device__ __forceinline__ void gemm_core(const float* __restrict__ x,
                                          const float* __restrict__ W,
                                          int N, int nloc, int k0, int bq,
                                          float acc[8]) {
    const float* xr = x + bq * 8 * HH + k0;
    const float* wp = W + (size_t)k0 * N + nloc;
#pragma unroll 2
    for (int h4 = 0; h4 < 512; h4 += 4) {
        float w0 = wp[(size_t)(h4 + 0) * N];
        float w1 = wp[(size_t)(h4 + 1) * N];
        float w2 = wp[(size_t)(h4 + 2) * N];
        float w3 = wp[(size_t)(h4 + 3) * N];
#pragma unroll
        for (int b = 0; b < 8; ++b) {
            const float4 xv = *reinterpret_cast<const float4*>(xr + b * HH + h4);
            acc[b] = fmaf(xv.x, w0, acc[b]);
            acc[b] = fmaf(xv.y, w1, acc[b]);
            acc[b] = fmaf(xv.z, w2, acc[b]);
            acc[b] = fmaf(xv.w, w3, acc[b]);
        }
    }
}

// ---------------- Kernel 1: fused QKV projection, K-split partials ----------------
// grid (96, 8), block 256. part layout: [split][b(32)][n(6144)]
__global__ __launch_bounds__(256) void gemm_qkv(const float* __restrict__ x,
                                                const float* __restrict__ wq,
                                                const float* __restrict__ wk,
                                                const float* __restrict__ wv,
                                                float* __restrict__ part) {
    const int t = threadIdx.x;
    const int lane_n = t & 63;
    const int bq = t >> 6;                 // wave id: rows [bq*8, bq*8+8)
    const int ng = blockIdx.x * 64 + lane_n;
    const int k0 = blockIdx.y * 512;

    const float* W;
    int nloc, N;
    if (ng < 4096)      { W = wq; nloc = ng;        N = 4096; }
    else if (ng < 5120) { W = wk; nloc = ng - 4096; N = 1024; }
    else                { W = wv; nloc = ng - 5120; N = 1024; }

    float acc[8] = {0.f, 0.f, 0.f, 0.f, 0.f, 0.f, 0.f, 0.f};
    gemm_core(x, W, N, nloc, k0, bq, acc);

#pragma unroll
    for (int b = 0; b < 8; ++b)
        part[((size_t)blockIdx.y * BB + bq * 8 + b) * NQK + ng] = acc[b];
}

// ---------------- Kernel 2: reduce K-split partials + rotate q/k, scatter v ----
// grid 1536 (1024 q-heads*b, 256 k, 256 v), block 128.
// q_rot layout: [pair = hkv*32+b][g][e]   (pair-major, 512 floats per pair)
// k_new/v_new:  [pair][e]
__global__ __launch_bounds__(128) void rot_kernel(const float* __restrict__ part,
                                                  const float* __restrict__ rot,
                                                  float* __restrict__ q_rot,
                                                  float* __restrict__ k_new,
                                                  float* __restrict__ v_new) {
    const int blk = blockIdx.x;
    const int e = threadIdx.x;  // 0..127

    int kind, b, head;
    if (blk < 1024)      { kind = 0; b = blk >> 5;          head = blk & 31; }
    else if (blk < 1280) { kind = 1; b = (blk - 1024) >> 3; head = (blk - 1024) & 7; }
    else                 { kind = 2; b = (blk - 1280) >> 3; head = (blk - 1280) & 7; }

    const int ncol = (kind == 0) ? head * DD
                   : (kind == 1) ? 4096 + head * DD
                                 : 5120 + head * DD;

    float val = 0.f;
#pragma unroll
    for (int s = 0; s < KSPL; ++s)
        val += part[((size_t)s * BB + b) * NQK + ncol + e];

    if (kind == 2) {
        v_new[(size_t)(head * BB + b) * DD + e] = val;
        return;
    }

    __shared__ float row[DD];
    row[e] = val;
    __syncthreads();

    float acc = 0.f;
#pragma unroll 4
    for (int d = 0; d < DD; ++d)
        acc = fmaf(row[d], rot[d * DD + e], acc);

    if (kind == 0) {
        acc *= 0.08838834764831845f;  // D^-0.5
        const int hk = head >> 2, g = head & 3;
        q_rot[((size_t)(hk * BB + b) * GG + g) * DD + e] = acc;
    } else {
        k_new[(size_t)(head * BB + b) * DD + e] = acc;
    }
}

// ---------------- Kernel 3: flash-decode attention, split partials ----------------
// grid (256 pairs, ASPL splits), block 256 (4 waves).
// Wave layout: lane = sub(2b: position offset 0..3) x li(4b: dims [li*8, li*8+8))
__global__ __launch_bounds__(256) void attn_kernel(const float* __restrict__ q_rot,
                                                   const float* __restrict__ k_new,
                                                   const float* __restrict__ v_new,
                                                   const float* __restrict__ cache_k,
                                                   const float* __restrict__ cache_v,
                                                   const int* __restrict__ spp,
                                                   const int* __restrict__ cpp,
                                                   float* __restrict__ m_part,
                                                   float* __restrict__ l_part,
                                                   float* __restrict__ o_part) {
    const int pair  = blockIdx.x;       // hkv*32 + b
    const int split = blockIdx.y;
    const int start_pos   = *spp;
    const int current_pos = *cpp;
    const int layer_slice = min(start_pos + 1, SWIN);

    const int tid  = threadIdx.x;
    const int w    = tid >> 6;
    const int lane = tid & 63;
    const int sub  = lane >> 4;   // position sub-slot 0..3
    const int li   = lane & 15;   // dim slice owner

    // load q fragments: q_rot[pair][g][li*8 .. li*8+8)
    const float* qb = q_rot + (size_t)pair * (GG * DD) + li * 8;
    float4 qa[GG], qc[GG];
#pragma unroll
    for (int g = 0; g < GG; ++g) {
        qa[g] = *reinterpret_cast<const float4*>(qb + g * DD);
        qc[g] = *reinterpret_cast<const float4*>(qb + g * DD + 4);
    }

    const int nstreams = ASPL * 4;
    const int chunk = (layer_slice + nstreams - 1) / nstreams;
    const int wsid = split * 4 + w;
    const int p_begin = wsid * chunk;
    const int p_end = min(p_begin + chunk, layer_slice);

    const float* kc = cache_k + (size_t)pair * SWIN * DD;
    const float* vc = cache_v + (size_t)pair * SWIN * DD;
    const float* kn = k_new + (size_t)pair * DD;
    const float* vn = v_new + (size_t)pair * DD;

    float M[GG] = {-1e30f, -1e30f, -1e30f, -1e30f};
    float L[GG] = {0.f, 0.f, 0.f, 0.f};
    float4 oa[GG], oc[GG];
#pragma unroll
    for (int g = 0; g < GG; ++g) {
        oa[g] = make_float4(0.f, 0.f, 0.f, 0.f);
        oc[g] = make_float4(0.f, 0.f, 0.f, 0.f);
    }

    for (int p0 = p_begin; p0 < p_end; p0 += 4) {
        const int p = p0 + sub;
        const bool valid = (p < p_end);
        const int pc = valid ? p : p0;

        const float* krow = kc + (size_t)pc * DD;
        const float* vrow = vc + (size_t)pc * DD;
        if (pc == current_pos) { krow = kn; vrow = vn; }

        const float4 k0v = *reinterpret_cast<const float4*>(krow + li * 8);
        const float4 k1v = *reinterpret_cast<const float4*>(krow + li * 8 + 4);
        const float4 v0v = *reinterpret_cast<const float4*>(vrow + li * 8);
        const float4 v1v = *reinterpret_cast<const float4*>(vrow + li * 8 + 4);

        float s[GG];
#pragma unroll
        for (int g = 0; g < GG; ++g) {
            float a = 0.f;
            a = fmaf(qa[g].x, k0v.x, a);
            a = fmaf(qa[g].y, k0v.y, a);
            a = fmaf(qa[g].z, k0v.z, a);
            a = fmaf(qa[g].w, k0v.w, a);
            a = fmaf(qc[g].x, k1v.x, a);
            a = fmaf(qc[g].y, k1v.y, a);
            a = fmaf(qc[g].z, k1v.z, a);
            a = fmaf(qc[g].w, k1v.w, a);
            s[g] = a;
        }
        // reduce over the 16-lane dim group (xor bits 0..3)
#pragma unroll
        for (int off = 1; off <= 8; off <<= 1) {
#pragma unroll
            for (int g = 0; g < GG; ++g) s[g] += xsh(s[g], off);
        }
        if (!valid) {
#pragma unroll
            for (int g = 0; g < GG; ++g) s[g] = -INFINITY;
        }
        // online softmax update (per 16-lane group, replicated)
#pragma unroll
        for (int g = 0; g < GG; ++g) {
            const float nM = fmaxf(M[g], s[g]);
            const float e0 = exp2f((M[g] - nM) * L2E);
            const float pe = exp2f((s[g] - nM) * L2E);
            M[g] = nM;
            L[g] = fmaf(L[g], e0, pe);
            oa[g].x = fmaf(oa[g].x, e0, pe * v0v.x);
            oa[g].y = fmaf(oa[g].y, e0, pe * v0v.y);
            oa[g].z = fmaf(oa[g].z, e0, pe * v0v.z);
            oa[g].w = fmaf(oa[g].w, e0, pe * v0v.w);
            oc[g].x = fmaf(oc[g].x, e0, pe * v1v.x);
            oc[g].y = fmaf(oc[g].y, e0, pe * v1v.y);
            oc[g].z = fmaf(oc[g].z, e0, pe * v1v.z);
            oc[g].w = fmaf(oc[g].w, e0, pe * v1v.w);
        }
    }

    // merge the 4 position sub-groups within the wave (xor bits 4,5)
#pragma unroll
    for (int off = 16; off <= 32; off <<= 1) {
#pragma unroll
        for (int g = 0; g < GG; ++g) {
            const float Mo = xsh(M[g], off);
            const float Lo = xsh(L[g], off);
            const float nM = fmaxf(M[g], Mo);
            const float e0 = exp2f((M[g] - nM) * L2E);
            const float e1 = exp2f((Mo - nM) * L2E);
            M[g] = nM;
            L[g] = L[g] * e0 + Lo * e1;
            oa[g].x = oa[g].x * e0 + xsh(oa[g].x, off) * e1;
            oa[g].y = oa[g].y * e0 + xsh(oa[g].y, off) * e1;
            oa[g].z = oa[g].z * e0 + xsh(oa[g].z, off) * e1;
            oa[g].w = oa[g].w * e0 + xsh(oa[g].w, off) * e1;
            oc[g].x = oc[g].x * e0 + xsh(oc[g].x, off) * e1;
            oc[g].y = oc[g].y * e0 + xsh(oc[g].y, off) * e1;
            oc[g].z = oc[g].z * e0 + xsh(oc[g].z, off) * e1;
            oc[g].w = oc[g].w * e0 + xsh(oc[g].w, off) * e1;
        }
    }

    // merge the 4 waves via LDS
    __shared__ float sM[4][GG], sL[4][GG];
    __shared__ float sO[4][GG][DD];
    if (sub == 0) {
#pragma unroll
        for (int g = 0; g < GG; ++g) {
            sO[w][g][li * 8 + 0] = oa[g].x;
            sO[w][g][li * 8 + 1] = oa[g].y;
            sO[w][g][li * 8 + 2] = oa[g].z;
            sO[w][g][li * 8 + 3] = oa[g].w;
            sO[w][g][li * 8 + 4] = oc[g].x;
            sO[w][g][li * 8 + 5] = oc[g].y;
            sO[w][g][li * 8 + 6] = oc[g].z;
            sO[w][g][li * 8 + 7] = oc[g].w;
            if (li == 0) { sM[w][g] = M[g]; sL[w][g] = L[g]; }
        }
    }
    __syncthreads();

    for (int item = tid; item < GG * DD; item += 256) {
        const int g = item >> 7;
        const int d = item & 127;
        const float m0 = sM[0][g], m1 = sM[1][g], m2 = sM[2][g], m3 = sM[3][g];
        const float nM = fmaxf(fmaxf(m0, m1), fmaxf(m2, m3));
        const float e0 = exp2f((m0 - nM) * L2E);
        const float e1 = exp2f((m1 - nM) * L2E);
        const float e2 = exp2f((m2 - nM) * L2E);
        const float e3 = exp2f((m3 - nM) * L2E);
        const float lt = sL[0][g] * e0 + sL[1][g] * e1 + sL[2][g] * e2 + sL[3][g] * e3;
        const float od = sO[0][g][d] * e0 + sO[1][g][d] * e1 +
                         sO[2][g][d] * e2 + sO[3][g][d] * e3;
        const size_t base = ((size_t)pair * GG + g) * ASPL + split;
        if (d == 0) { m_part[base] = nM; l_part[base] = lt; }
        o_part[base * DD + d] = od;
    }
}

// ---------------- Kernel 4: merge sequence splits (LSE), write attn_out[b][n] ----
__global__ __launch_bounds__(256) void attn_reduce(const float* __restrict__ m_part,
                                                   const float* __restrict__ l_part,
                                                   const float* __restrict__ o_part,
                                                   float* __restrict__ attn_out) {
    const int idx = blockIdx.x * 256 + threadIdx.x;  // < 256*4*128
    const int d = idx & 127;
    const int pg = idx >> 7;  // pair*4 + g

    float nM = -1e30f;
#pragma unroll
    for (int s = 0; s < ASPL; ++s) nM = fmaxf(nM, m_part[pg * ASPL + s]);

    float lt = 0.f, od = 0.f;
#pragma unroll
    for (int s = 0; s < ASPL; ++s) {
        const float e = exp2f((m_part[pg * ASPL + s] - nM) * L2E);
        lt = fmaf(l_part[pg * ASPL + s], e, lt);
        od = fmaf(o_part[(size_t)(pg * ASPL + s) * DD + d], e, od);
    }

    const int pair = pg >> 2, g = pg & 3;
    const int h = pair >> 5, b = pair & 31;
    attn_out[(size_t)b * HH + (h * GG + g) * DD + d] = od / fmaxf(lt, 1e-30f);
}

// ---------------- Kernel 5: dense output projection, K-split partials ----------------
// grid (64, 8), block 256. part layout: [split][b(32)][n(4096)]
__global__ __launch_bounds__(256) void gemm_dense(const float* __restrict__ x,
                                                  const float* __restrict__ wo,
                                                  float* __restrict__ part) {
    const int t = threadIdx.x;
    const int lane_n = t & 63;
    const int bq = t >> 6;
    const int ng = blockIdx.x * 64 + lane_n;
    const int k0 = blockIdx.y * 512;

    float acc[8] = {0.f, 0.f, 0.f, 0.f, 0.f, 0.f, 0.f, 0.f};
    gemm_core(x, wo, HH, ng, k0, bq, acc);

#pragma unroll
    for (int b = 0; b < 8; ++b)
        part[((size_t)blockIdx.y * BB + bq * 8 + b) * HH + ng] = acc[b];
}

// ---------------- Kernel 6: reduce dense partials -> d_out ----------------
__global__ __launch_bounds__(256) void reduce_dense(const float* __restrict__ part,
                                                    float* __restrict__ out) {
    const int idx = blockIdx.x * 256 + threadIdx.x;  // < 32*4096
    float a = 0.f;
#pragma unroll
    for (int s = 0; s < KSPL; ++s) a += part[(size_t)s * (BB * HH) + idx];
    out[idx] = a;
}

extern "C" void kernel_launch(void* const* d_in, const int* in_sizes, int n_in,
                              void* d_out, int out_size, void* d_ws, size_t ws_size,
                              hipStream_t stream) {
    const float* x       = (const float*)d_in[0];
    const float* wq      = (const float*)d_in[1];
    const float* wk      = (const float*)d_in[2];
    const float* wv      = (const float*)d_in[3];
    const float* wo      = (const float*)d_in[4];
    const float* rot     = (const float*)d_in[5];
    const float* cache_k = (const float*)d_in[6];
    const float* cache_v = (const float*)d_in[7];
    const int*   spp     = (const int*)d_in[8];
    const int*   cpp     = (const int*)d_in[9];
    float* out = (float*)d_out;
    float* ws  = (float*)d_ws;

    // workspace layout (floats)
    float* part_qkv = ws;                       // 8*32*6144   = 1,572,864
    float* q_rot    = part_qkv + 1572864;       // 8*32*4*128  =   131,072
    float* k_new    = q_rot + 131072;           // 8*32*128    =    32,768
    float* v_new    = k_new + 32768;            //             =    32,768
    float* m_part   = v_new + 32768;            // 256*4*16    =    16,384
    float* l_part   = m_part + 16384;           //             =    16,384
    float* o_part   = l_part + 16384;           // 256*4*16*128= 2,097,152
    float* attn_out = o_part + 2097152;         // 32*4096     =   131,072
    float* part_d   = attn_out + 131072;        // 8*32*4096   = 1,048,576

    gemm_qkv<<<dim3(96, KSPL), 256, 0, stream>>>(x, wq, wk, wv, part_qkv);
    rot_kernel<<<1536, 128, 0, stream>>>(part_qkv, rot, q_rot, k_new, v_new);
    attn_kernel<<<dim3(256, ASPL), 256, 0, stream>>>(q_rot, k_new, v_new,
                                                     cache_k, cache_v, spp, cpp,
                                                     m_part, l_part, o_part);
    attn_reduce<<<512, 256, 0, stream>>>(m_part, l_part, o_part, attn_out);
    gemm_dense<<<dim3(64, KSPL), 256, 0, stream>>>(attn_out, wo, part_d);
    reduce_dense<<<512, 256, 0, stream>>>(part_d, out);
}

// Round 2
// 404.013 us; speedup vs baseline: 1.0874x; 1.0874x over previous
//
#include <hip/hip_runtime.h>

#define L2E 1.4426950408889634f

#define BB   32      // batch
#define HH   4096    // hidden
#define NH   32      // n heads
#define NKV  8       // n kv heads
#define GG   4       // NH/NKV
#define DD   128     // head dim
#define SWIN 4096    // cache window
#define NQK  6144    // 4096 q cols + 1024 k + 1024 v
#define KSPL 8       // K-split for projections
#define ASPL 8       // sequence splits for attention

typedef float f4 __attribute__((ext_vector_type(4)));

__device__ __forceinline__ float xsh(float v, int off) {
    return __shfl_xor(v, off, 64);
}

__device__ __forceinline__ f4 ntload(const float* p) {
    return __builtin_nontemporal_load(reinterpret_cast<const f4*>(p));
}

// ---------------- GEMM core: rows [bq*8, bq*8+8) of x (32xK=4096) times one
// column nloc of W (row-major K x N), K-chunk [k0, k0+512). ----------------
__device__ __forceinline__ void gemm_core(const float* __restrict__ x,
                                          const float* __restrict__ W,
                                          int N, int nloc, int k0, int bq,
                                          float acc[8]) {
    const float* xr = x + bq * 8 * HH + k0;
    const float* wp = W + (size_t)k0 * N + nloc;
#pragma unroll 4
    for (int h4 = 0; h4 < 512; h4 += 4) {
        float w0 = wp[(size_t)(h4 + 0) * N];
        float w1 = wp[(size_t)(h4 + 1) * N];
        float w2 = wp[(size_t)(h4 + 2) * N];
        float w3 = wp[(size_t)(h4 + 3) * N];
#pragma unroll
        for (int b = 0; b < 8; ++b) {
            const float4 xv = *reinterpret_cast<const float4*>(xr + b * HH + h4);
            acc[b] = fmaf(xv.x, w0, acc[b]);
            acc[b] = fmaf(xv.y, w1, acc[b]);
            acc[b] = fmaf(xv.z, w2, acc[b]);
            acc[b] = fmaf(xv.w, w3, acc[b]);
        }
    }
}

// ---------------- Kernel 1: fused QKV projection, K-split partials ----------------
// grid (96, 8), block 256. part layout: [split][b(32)][n(6144)]
__global__ __launch_bounds__(256) void gemm_qkv(const float* __restrict__ x,
                                                const float* __restrict__ wq,
                                                const float* __restrict__ wk,
                                                const float* __restrict__ wv,
                                                float* __restrict__ part) {
    const int t = threadIdx.x;
    const int lane_n = t & 63;
    const int bq = t >> 6;                 // wave id: rows [bq*8, bq*8+8)
    const int ng = blockIdx.x * 64 + lane_n;
    const int k0 = blockIdx.y * 512;

    const float* W;
    int nloc, N;
    if (ng < 4096)      { W = wq; nloc = ng;        N = 4096; }
    else if (ng < 5120) { W = wk; nloc = ng - 4096; N = 1024; }
    else                { W = wv; nloc = ng - 5120; N = 1024; }

    float acc[8] = {0.f, 0.f, 0.f, 0.f, 0.f, 0.f, 0.f, 0.f};
    gemm_core(x, W, N, nloc, k0, bq, acc);

#pragma unroll
    for (int b = 0; b < 8; ++b)
        part[((size_t)blockIdx.y * BB + bq * 8 + b) * NQK + ng] = acc[b];
}

// ---------------- Kernel 2: reduce K-split partials + rotate q/k, scatter v ----
__global__ __launch_bounds__(128) void rot_kernel(const float* __restrict__ part,
                                                  const float* __restrict__ rot,
                                                  float* __restrict__ q_rot,
                                                  float* __restrict__ k_new,
                                                  float* __restrict__ v_new) {
    const int blk = blockIdx.x;
    const int e = threadIdx.x;  // 0..127

    int kind, b, head;
    if (blk < 1024)      { kind = 0; b = blk >> 5;          head = blk & 31; }
    else if (blk < 1280) { kind = 1; b = (blk - 1024) >> 3; head = (blk - 1024) & 7; }
    else                 { kind = 2; b = (blk - 1280) >> 3; head = (blk - 1280) & 7; }

    const int ncol = (kind == 0) ? head * DD
                   : (kind == 1) ? 4096 + head * DD
                                 : 5120 + head * DD;

    float val = 0.f;
#pragma unroll
    for (int s = 0; s < KSPL; ++s)
        val += part[((size_t)s * BB + b) * NQK + ncol + e];

    if (kind == 2) {
        v_new[(size_t)(head * BB + b) * DD + e] = val;
        return;
    }

    __shared__ float row[DD];
    row[e] = val;
    __syncthreads();

    float acc = 0.f;
#pragma unroll 4
    for (int d = 0; d < DD; ++d)
        acc = fmaf(row[d], rot[d * DD + e], acc);

    if (kind == 0) {
        acc *= 0.08838834764831845f;  // D^-0.5
        const int hk = head >> 2, g = head & 3;
        q_rot[((size_t)(hk * BB + b) * GG + g) * DD + e] = acc;
    } else {
        k_new[(size_t)(head * BB + b) * DD + e] = acc;
    }
}

// ---------------- Kernel 3: flash-decode attention, 2-deep pipelined ----------------
// grid (256 pairs, ASPL splits), block 256 (4 waves).
// Wave layout: lane = sub(2b: position offset 0..3) x li(4b: dims [li*8, li*8+8))
__global__ __launch_bounds__(256) void attn_kernel(const float* __restrict__ q_rot,
                                                   const float* __restrict__ k_new,
                                                   const float* __restrict__ v_new,
                                                   const float* __restrict__ cache_k,
                                                   const float* __restrict__ cache_v,
                                                   const int* __restrict__ spp,
                                                   const int* __restrict__ cpp,
                                                   float* __restrict__ m_part,
                                                   float* __restrict__ l_part,
                                                   float* __restrict__ o_part) {
    const int pair  = blockIdx.x;       // hkv*32 + b
    const int split = blockIdx.y;
    const int start_pos   = *spp;
    const int current_pos = *cpp;
    const int layer_slice = min(start_pos + 1, SWIN);

    const int tid  = threadIdx.x;
    const int w    = tid >> 6;
    const int lane = tid & 63;
    const int sub  = lane >> 4;   // position sub-slot 0..3
    const int li   = lane & 15;   // dim slice owner

    const float* qb = q_rot + (size_t)pair * (GG * DD) + li * 8;
    f4 qa[GG], qc[GG];
#pragma unroll
    for (int g = 0; g < GG; ++g) {
        qa[g] = *reinterpret_cast<const f4*>(qb + g * DD);
        qc[g] = *reinterpret_cast<const f4*>(qb + g * DD + 4);
    }

    const int nstreams = ASPL * 4;
    const int chunk = (layer_slice + nstreams - 1) / nstreams;
    const int wsid = split * 4 + w;
    const int p_begin = wsid * chunk;
    const int p_end = min(p_begin + chunk, layer_slice);

    const float* kc = cache_k + (size_t)pair * SWIN * DD;
    const float* vc = cache_v + (size_t)pair * SWIN * DD;
    const float* kn = k_new + (size_t)pair * DD;
    const float* vn = v_new + (size_t)pair * DD;

    float M[GG] = {-1e30f, -1e30f, -1e30f, -1e30f};
    float L[GG] = {0.f, 0.f, 0.f, 0.f};
    f4 oa[GG], oc[GG];
#pragma unroll
    for (int g = 0; g < GG; ++g) {
        oa[g] = (f4){0.f, 0.f, 0.f, 0.f};
        oc[g] = (f4){0.f, 0.f, 0.f, 0.f};
    }

    // --- prologue: load first position group (clamped, branch-free) ---
    auto rowptrs = [&](int p, const float*& kr, const float*& vr) {
        kr = kc + (size_t)p * DD;
        vr = vc + (size_t)p * DD;
        if (p == current_pos) { kr = kn; vr = vn; }
    };

    const int off0 = li * 8;
    int pcl = min(p_begin + sub, layer_slice - 1);
    const float *kr, *vr;
    rowptrs(pcl, kr, vr);
    f4 ck0 = ntload(kr + off0), ck1 = ntload(kr + off0 + 4);
    f4 cv0 = ntload(vr + off0), cv1 = ntload(vr + off0 + 4);

    for (int p0 = p_begin; p0 < p_end; p0 += 4) {
        // prefetch next group (unconditional, clamped)
        const int pn = min(p0 + 4 + sub, layer_slice - 1);
        const float *nkr, *nvr;
        rowptrs(pn, nkr, nvr);
        const f4 nk0 = ntload(nkr + off0), nk1 = ntload(nkr + off0 + 4);
        const f4 nv0 = ntload(nvr + off0), nv1 = ntload(nvr + off0 + 4);

        const int p = p0 + sub;
        const bool valid = (p < p_end);

        float s[GG];
#pragma unroll
        for (int g = 0; g < GG; ++g) {
            float a = 0.f;
            a = fmaf(qa[g].x, ck0.x, a);
            a = fmaf(qa[g].y, ck0.y, a);
            a = fmaf(qa[g].z, ck0.z, a);
            a = fmaf(qa[g].w, ck0.w, a);
            a = fmaf(qc[g].x, ck1.x, a);
            a = fmaf(qc[g].y, ck1.y, a);
            a = fmaf(qc[g].z, ck1.z, a);
            a = fmaf(qc[g].w, ck1.w, a);
            s[g] = a;
        }
#pragma unroll
        for (int off = 1; off <= 8; off <<= 1) {
#pragma unroll
            for (int g = 0; g < GG; ++g) s[g] += xsh(s[g], off);
        }
        if (!valid) {
#pragma unroll
            for (int g = 0; g < GG; ++g) s[g] = -INFINITY;
        }
#pragma unroll
        for (int g = 0; g < GG; ++g) {
            const float nM = fmaxf(M[g], s[g]);
            const float e0 = exp2f((M[g] - nM) * L2E);
            const float pe = exp2f((s[g] - nM) * L2E);
            M[g] = nM;
            L[g] = fmaf(L[g], e0, pe);
            oa[g].x = fmaf(oa[g].x, e0, pe * cv0.x);
            oa[g].y = fmaf(oa[g].y, e0, pe * cv0.y);
            oa[g].z = fmaf(oa[g].z, e0, pe * cv0.z);
            oa[g].w = fmaf(oa[g].w, e0, pe * cv0.w);
            oc[g].x = fmaf(oc[g].x, e0, pe * cv1.x);
            oc[g].y = fmaf(oc[g].y, e0, pe * cv1.y);
            oc[g].z = fmaf(oc[g].z, e0, pe * cv1.z);
            oc[g].w = fmaf(oc[g].w, e0, pe * cv1.w);
        }

        ck0 = nk0; ck1 = nk1; cv0 = nv0; cv1 = nv1;
    }

    // merge the 4 position sub-groups within the wave (xor bits 4,5)
#pragma unroll
    for (int off = 16; off <= 32; off <<= 1) {
#pragma unroll
        for (int g = 0; g < GG; ++g) {
            const float Mo = xsh(M[g], off);
            const float Lo = xsh(L[g], off);
            const float nM = fmaxf(M[g], Mo);
            const float e0 = exp2f((M[g] - nM) * L2E);
            const float e1 = exp2f((Mo - nM) * L2E);
            M[g] = nM;
            L[g] = L[g] * e0 + Lo * e1;
            oa[g].x = oa[g].x * e0 + xsh(oa[g].x, off) * e1;
            oa[g].y = oa[g].y * e0 + xsh(oa[g].y, off) * e1;
            oa[g].z = oa[g].z * e0 + xsh(oa[g].z, off) * e1;
            oa[g].w = oa[g].w * e0 + xsh(oa[g].w, off) * e1;
            oc[g].x = oc[g].x * e0 + xsh(oc[g].x, off) * e1;
            oc[g].y = oc[g].y * e0 + xsh(oc[g].y, off) * e1;
            oc[g].z = oc[g].z * e0 + xsh(oc[g].z, off) * e1;
            oc[g].w = oc[g].w * e0 + xsh(oc[g].w, off) * e1;
        }
    }

    // merge the 4 waves via LDS
    __shared__ float sM[4][GG], sL[4][GG];
    __shared__ float sO[4][GG][DD];
    if (sub == 0) {
#pragma unroll
        for (int g = 0; g < GG; ++g) {
            sO[w][g][li * 8 + 0] = oa[g].x;
            sO[w][g][li * 8 + 1] = oa[g].y;
            sO[w][g][li * 8 + 2] = oa[g].z;
            sO[w][g][li * 8 + 3] = oa[g].w;
            sO[w][g][li * 8 + 4] = oc[g].x;
            sO[w][g][li * 8 + 5] = oc[g].y;
            sO[w][g][li * 8 + 6] = oc[g].z;
            sO[w][g][li * 8 + 7] = oc[g].w;
            if (li == 0) { sM[w][g] = M[g]; sL[w][g] = L[g]; }
        }
    }
    __syncthreads();

    for (int item = tid; item < GG * DD; item += 256) {
        const int g = item >> 7;
        const int d = item & 127;
        const float m0 = sM[0][g], m1 = sM[1][g], m2 = sM[2][g], m3 = sM[3][g];
        const float nM = fmaxf(fmaxf(m0, m1), fmaxf(m2, m3));
        const float e0 = exp2f((m0 - nM) * L2E);
        const float e1 = exp2f((m1 - nM) * L2E);
        const float e2 = exp2f((m2 - nM) * L2E);
        const float e3 = exp2f((m3 - nM) * L2E);
        const float lt = sL[0][g] * e0 + sL[1][g] * e1 + sL[2][g] * e2 + sL[3][g] * e3;
        const float od = sO[0][g][d] * e0 + sO[1][g][d] * e1 +
                         sO[2][g][d] * e2 + sO[3][g][d] * e3;
        const size_t base = ((size_t)pair * GG + g) * ASPL + split;
        if (d == 0) { m_part[base] = nM; l_part[base] = lt; }
        o_part[base * DD + d] = od;
    }
}

// ---------------- Kernel 4: merge sequence splits (LSE), write attn_out[b][n] ----
__global__ __launch_bounds__(256) void attn_reduce(const float* __restrict__ m_part,
                                                   const float* __restrict__ l_part,
                                                   const float* __restrict__ o_part,
                                                   float* __restrict__ attn_out) {
    const int idx = blockIdx.x * 256 + threadIdx.x;  // < 256*4*128
    const int d = idx & 127;
    const int pg = idx >> 7;  // pair*4 + g

    float nM = -1e30f;
#pragma unroll
    for (int s = 0; s < ASPL; ++s) nM = fmaxf(nM, m_part[pg * ASPL + s]);

    float lt = 0.f, od = 0.f;
#pragma unroll
    for (int s = 0; s < ASPL; ++s) {
        const float e = exp2f((m_part[pg * ASPL + s] - nM) * L2E);
        lt = fmaf(l_part[pg * ASPL + s], e, lt);
        od = fmaf(o_part[(size_t)(pg * ASPL + s) * DD + d], e, od);
    }

    const int pair = pg >> 2, g = pg & 3;
    const int h = pair >> 5, b = pair & 31;
    attn_out[(size_t)b * HH + (h * GG + g) * DD + d] = od / fmaxf(lt, 1e-30f);
}

// ---------------- Kernel 5: dense output projection, K-split partials ----------------
__global__ __launch_bounds__(256) void gemm_dense(const float* __restrict__ x,
                                                  const float* __restrict__ wo,
                                                  float* __restrict__ part) {
    const int t = threadIdx.x;
    const int lane_n = t & 63;
    const int bq = t >> 6;
    const int ng = blockIdx.x * 64 + lane_n;
    const int k0 = blockIdx.y * 512;

    float acc[8] = {0.f, 0.f, 0.f, 0.f, 0.f, 0.f, 0.f, 0.f};
    gemm_core(x, wo, HH, ng, k0, bq, acc);

#pragma unroll
    for (int b = 0; b < 8; ++b)
        part[((size_t)blockIdx.y * BB + bq * 8 + b) * HH + ng] = acc[b];
}

// ---------------- Kernel 6: reduce dense partials -> d_out ----------------
__global__ __launch_bounds__(256) void reduce_dense(const float* __restrict__ part,
                                                    float* __restrict__ out) {
    const int idx = blockIdx.x * 256 + threadIdx.x;  // < 32*4096
    float a = 0.f;
#pragma unroll
    for (int s = 0; s < KSPL; ++s) a += part[(size_t)s * (BB * HH) + idx];
    out[idx] = a;
}

extern "C" void kernel_launch(void* const* d_in, const int* in_sizes, int n_in,
                              void* d_out, int out_size, void* d_ws, size_t ws_size,
                              hipStream_t stream) {
    const float* x       = (const float*)d_in[0];
    const float* wq      = (const float*)d_in[1];
    const float* wk      = (const float*)d_in[2];
    const float* wv      = (const float*)d_in[3];
    const float* wo      = (const float*)d_in[4];
    const float* rot     = (const float*)d_in[5];
    const float* cache_k = (const float*)d_in[6];
    const float* cache_v = (const float*)d_in[7];
    const int*   spp     = (const int*)d_in[8];
    const int*   cpp     = (const int*)d_in[9];
    float* out = (float*)d_out;
    float* ws  = (float*)d_ws;

    // workspace layout (floats)
    float* part_qkv = ws;                       // 8*32*6144   = 1,572,864
    float* q_rot    = part_qkv + 1572864;       // 8*32*4*128  =   131,072
    float* k_new    = q_rot + 131072;           // 8*32*128    =    32,768
    float* v_new    = k_new + 32768;            //             =    32,768
    float* m_part   = v_new + 32768;            // 256*4*8     =     8,192
    float* l_part   = m_part + 8192;            //             =     8,192
    float* o_part   = l_part + 8192;            // 256*4*8*128 = 1,048,576
    float* attn_out = o_part + 1048576;         // 32*4096     =   131,072
    float* part_d   = attn_out + 131072;        // 8*32*4096   = 1,048,576

    gemm_qkv<<<dim3(96, KSPL), 256, 0, stream>>>(x, wq, wk, wv, part_qkv);
    rot_kernel<<<1536, 128, 0, stream>>>(part_qkv, rot, q_rot, k_new, v_new);
    attn_kernel<<<dim3(256, ASPL), 256, 0, stream>>>(q_rot, k_new, v_new,
                                                     cache_k, cache_v, spp, cpp,
                                                     m_part, l_part, o_part);
    attn_reduce<<<512, 256, 0, stream>>>(m_part, l_part, o_part, attn_out);
    gemm_dense<<<dim3(64, KSPL), 256, 0, stream>>>(attn_out, wo, part_d);
    reduce_dense<<<512, 256, 0, stream>>>(part_d, out);
}

// Round 3
// 398.711 us; speedup vs baseline: 1.1019x; 1.0133x over previous
//
#include <hip/hip_runtime.h>

#define L2E 1.4426950408889634f

#define BB   32      // batch
#define HH   4096    // hidden
#define NH   32      // n heads
#define NKV  8       // n kv heads
#define GG   4       // NH/NKV
#define DD   128     // head dim
#define SWIN 4096    // cache window
#define NQK  6144    // 4096 q cols + 1024 k + 1024 v
#define KSPL 8       // K-split for projections
#define ASPL 8       // sequence splits for attention

typedef float f4 __attribute__((ext_vector_type(4)));

__device__ __forceinline__ float xsh(float v, int off) {
    return __shfl_xor(v, off, 64);
}

__device__ __forceinline__ f4 ntload(const float* p) {
    return __builtin_nontemporal_load(reinterpret_cast<const f4*>(p));
}

// ---------------- GEMM core: rows [bq*8, bq*8+8) of x (32xK=4096) times one
// column nloc of W (row-major K x N), K-chunk [k0, k0+512). ----------------
__device__ __forceinline__ void gemm_core(const float* __restrict__ x,
                                          const float* __restrict__ W,
                                          int N, int nloc, int k0, int bq,
                                          float acc[8]) {
    const float* xr = x + bq * 8 * HH + k0;
    const float* wp = W + (size_t)k0 * N + nloc;
#pragma unroll 4
    for (int h4 = 0; h4 < 512; h4 += 4) {
        float w0 = wp[(size_t)(h4 + 0) * N];
        float w1 = wp[(size_t)(h4 + 1) * N];
        float w2 = wp[(size_t)(h4 + 2) * N];
        float w3 = wp[(size_t)(h4 + 3) * N];
#pragma unroll
        for (int b = 0; b < 8; ++b) {
            const float4 xv = *reinterpret_cast<const float4*>(xr + b * HH + h4);
            acc[b] = fmaf(xv.x, w0, acc[b]);
            acc[b] = fmaf(xv.y, w1, acc[b]);
            acc[b] = fmaf(xv.z, w2, acc[b]);
            acc[b] = fmaf(xv.w, w3, acc[b]);
        }
    }
}

// ---------------- Kernel 1: fused QKV projection, K-split partials ----------------
__global__ __launch_bounds__(256) void gemm_qkv(const float* __restrict__ x,
                                                const float* __restrict__ wq,
                                                const float* __restrict__ wk,
                                                const float* __restrict__ wv,
                                                float* __restrict__ part) {
    const int t = threadIdx.x;
    const int lane_n = t & 63;
    const int bq = t >> 6;
    const int ng = blockIdx.x * 64 + lane_n;
    const int k0 = blockIdx.y * 512;

    const float* W;
    int nloc, N;
    if (ng < 4096)      { W = wq; nloc = ng;        N = 4096; }
    else if (ng < 5120) { W = wk; nloc = ng - 4096; N = 1024; }
    else                { W = wv; nloc = ng - 5120; N = 1024; }

    float acc[8] = {0.f, 0.f, 0.f, 0.f, 0.f, 0.f, 0.f, 0.f};
    gemm_core(x, W, N, nloc, k0, bq, acc);

#pragma unroll
    for (int b = 0; b < 8; ++b)
        part[((size_t)blockIdx.y * BB + bq * 8 + b) * NQK + ng] = acc[b];
}

// ---------------- Kernel 2: reduce K-split partials + rotate q/k, scatter v ----
__global__ __launch_bounds__(128) void rot_kernel(const float* __restrict__ part,
                                                  const float* __restrict__ rot,
                                                  float* __restrict__ q_rot,
                                                  float* __restrict__ k_new,
                                                  float* __restrict__ v_new) {
    const int blk = blockIdx.x;
    const int e = threadIdx.x;  // 0..127

    int kind, b, head;
    if (blk < 1024)      { kind = 0; b = blk >> 5;          head = blk & 31; }
    else if (blk < 1280) { kind = 1; b = (blk - 1024) >> 3; head = (blk - 1024) & 7; }
    else                 { kind = 2; b = (blk - 1280) >> 3; head = (blk - 1280) & 7; }

    const int ncol = (kind == 0) ? head * DD
                   : (kind == 1) ? 4096 + head * DD
                                 : 5120 + head * DD;

    float val = 0.f;
#pragma unroll
    for (int s = 0; s < KSPL; ++s)
        val += part[((size_t)s * BB + b) * NQK + ncol + e];

    if (kind == 2) {
        v_new[(size_t)(head * BB + b) * DD + e] = val;
        return;
    }

    __shared__ float row[DD];
    row[e] = val;
    __syncthreads();

    float acc = 0.f;
#pragma unroll 4
    for (int d = 0; d < DD; ++d)
        acc = fmaf(row[d], rot[d * DD + e], acc);

    if (kind == 0) {
        acc *= 0.08838834764831845f;  // D^-0.5
        const int hk = head >> 2, g = head & 3;
        q_rot[((size_t)(hk * BB + b) * GG + g) * DD + e] = acc;
    } else {
        k_new[(size_t)(head * BB + b) * DD + e] = acc;
    }
}

// ---------------- Kernel 3: flash-decode attention ----------------
// grid (256 pairs, ASPL splits), block 256 (4 waves).
// Wave layout: lane = sub(1b: position offset 0..1) x li(5b: dim quad [li*4, li*4+4))
// K/V load per iteration = one dwordx4 per lane = 1 KB fully contiguous
// (positions p0 and p0+1 are consecutive rows).
__global__ __launch_bounds__(256) void attn_kernel(const float* __restrict__ q_rot,
                                                   const float* __restrict__ k_new,
                                                   const float* __restrict__ v_new,
                                                   const float* __restrict__ cache_k,
                                                   const float* __restrict__ cache_v,
                                                   const int* __restrict__ spp,
                                                   const int* __restrict__ cpp,
                                                   float* __restrict__ m_part,
                                                   float* __restrict__ l_part,
                                                   float* __restrict__ o_part) {
    const int pair  = blockIdx.x;       // hkv*32 + b
    const int split = blockIdx.y;
    const int start_pos   = *spp;
    const int current_pos = *cpp;
    const int layer_slice = min(start_pos + 1, SWIN);

    const int tid  = threadIdx.x;
    const int w    = tid >> 6;
    const int lane = tid & 63;
    const int sub  = lane >> 5;   // position sub-slot 0..1
    const int li   = lane & 31;   // dim quad owner

    const float* qb = q_rot + (size_t)pair * (GG * DD) + li * 4;
    f4 qa[GG];
#pragma unroll
    for (int g = 0; g < GG; ++g)
        qa[g] = *reinterpret_cast<const f4*>(qb + g * DD);

    const int nstreams = ASPL * 4;
    const int chunk = (layer_slice + nstreams - 1) / nstreams;
    const int wsid = split * 4 + w;
    const int p_begin = wsid * chunk;
    const int p_end = min(p_begin + chunk, layer_slice);

    const float* kc = cache_k + (size_t)pair * SWIN * DD;
    const float* vc = cache_v + (size_t)pair * SWIN * DD;
    const float* kn = k_new + (size_t)pair * DD;
    const float* vn = v_new + (size_t)pair * DD;

    float M[GG] = {-1e30f, -1e30f, -1e30f, -1e30f};
    float L[GG] = {0.f, 0.f, 0.f, 0.f};
    f4 oa[GG];
#pragma unroll
    for (int g = 0; g < GG; ++g) oa[g] = (f4){0.f, 0.f, 0.f, 0.f};

    const int off0 = li * 4;
    auto rowk = [&](int p) {
        return ((p == current_pos) ? kn : kc + (size_t)p * DD) + off0;
    };
    auto rowv = [&](int p) {
        return ((p == current_pos) ? vn : vc + (size_t)p * DD) + off0;
    };

    // prologue load
    const int pc0 = min(p_begin + sub, layer_slice - 1);
    f4 ck = ntload(rowk(pc0));
    f4 cv = ntload(rowv(pc0));

    for (int p0 = p_begin; p0 < p_end; p0 += 2) {
        // prefetch next position pair (clamped, unconditional)
        const int pn = min(p0 + 2 + sub, layer_slice - 1);
        const f4 nk = ntload(rowk(pn));
        const f4 nv = ntload(rowv(pn));

        const bool valid = (p0 + sub) < p_end;

        float s[GG];
#pragma unroll
        for (int g = 0; g < GG; ++g) {
            float a = 0.f;
            a = fmaf(qa[g].x, ck.x, a);
            a = fmaf(qa[g].y, ck.y, a);
            a = fmaf(qa[g].z, ck.z, a);
            a = fmaf(qa[g].w, ck.w, a);
            s[g] = a;
        }
#pragma unroll
        for (int off = 1; off <= 16; off <<= 1) {
#pragma unroll
            for (int g = 0; g < GG; ++g) s[g] += xsh(s[g], off);
        }
        if (!valid) {
#pragma unroll
            for (int g = 0; g < GG; ++g) s[g] = -INFINITY;
        }
#pragma unroll
        for (int g = 0; g < GG; ++g) {
            const float nM = fmaxf(M[g], s[g]);
            const float e0 = exp2f((M[g] - nM) * L2E);
            const float pe = exp2f((s[g] - nM) * L2E);
            M[g] = nM;
            L[g] = fmaf(L[g], e0, pe);
            oa[g].x = fmaf(oa[g].x, e0, pe * cv.x);
            oa[g].y = fmaf(oa[g].y, e0, pe * cv.y);
            oa[g].z = fmaf(oa[g].z, e0, pe * cv.z);
            oa[g].w = fmaf(oa[g].w, e0, pe * cv.w);
        }

        ck = nk; cv = nv;
    }

    // merge the 2 position sub-groups within the wave (xor bit 5)
    {
        const int off = 32;
#pragma unroll
        for (int g = 0; g < GG; ++g) {
            const float Mo = xsh(M[g], off);
            const float Lo = xsh(L[g], off);
            const float nM = fmaxf(M[g], Mo);
            const float e0 = exp2f((M[g] - nM) * L2E);
            const float e1 = exp2f((Mo - nM) * L2E);
            M[g] = nM;
            L[g] = L[g] * e0 + Lo * e1;
            oa[g].x = oa[g].x * e0 + xsh(oa[g].x, off) * e1;
            oa[g].y = oa[g].y * e0 + xsh(oa[g].y, off) * e1;
            oa[g].z = oa[g].z * e0 + xsh(oa[g].z, off) * e1;
            oa[g].w = oa[g].w * e0 + xsh(oa[g].w, off) * e1;
        }
    }

    // merge the 4 waves via LDS
    __shared__ float sM[4][GG], sL[4][GG];
    __shared__ float sO[4][GG][DD];
    if (sub == 0) {
#pragma unroll
        for (int g = 0; g < GG; ++g) {
            sO[w][g][off0 + 0] = oa[g].x;
            sO[w][g][off0 + 1] = oa[g].y;
            sO[w][g][off0 + 2] = oa[g].z;
            sO[w][g][off0 + 3] = oa[g].w;
            if (li == 0) { sM[w][g] = M[g]; sL[w][g] = L[g]; }
        }
    }
    __syncthreads();

    for (int item = tid; item < GG * DD; item += 256) {
        const int g = item >> 7;
        const int d = item & 127;
        const float m0 = sM[0][g], m1 = sM[1][g], m2 = sM[2][g], m3 = sM[3][g];
        const float nM = fmaxf(fmaxf(m0, m1), fmaxf(m2, m3));
        const float e0 = exp2f((m0 - nM) * L2E);
        const float e1 = exp2f((m1 - nM) * L2E);
        const float e2 = exp2f((m2 - nM) * L2E);
        const float e3 = exp2f((m3 - nM) * L2E);
        const float lt = sL[0][g] * e0 + sL[1][g] * e1 + sL[2][g] * e2 + sL[3][g] * e3;
        const float od = sO[0][g][d] * e0 + sO[1][g][d] * e1 +
                         sO[2][g][d] * e2 + sO[3][g][d] * e3;
        const size_t base = ((size_t)pair * GG + g) * ASPL + split;
        if (d == 0) { m_part[base] = nM; l_part[base] = lt; }
        o_part[base * DD + d] = od;
    }
}

// ---------------- Kernel 4: merge sequence splits (LSE), write attn_out[b][n] ----
__global__ __launch_bounds__(256) void attn_reduce(const float* __restrict__ m_part,
                                                   const float* __restrict__ l_part,
                                                   const float* __restrict__ o_part,
                                                   float* __restrict__ attn_out) {
    const int idx = blockIdx.x * 256 + threadIdx.x;  // < 256*4*128
    const int d = idx & 127;
    const int pg = idx >> 7;  // pair*4 + g

    float nM = -1e30f;
#pragma unroll
    for (int s = 0; s < ASPL; ++s) nM = fmaxf(nM, m_part[pg * ASPL + s]);

    float lt = 0.f, od = 0.f;
#pragma unroll
    for (int s = 0; s < ASPL; ++s) {
        const float e = exp2f((m_part[pg * ASPL + s] - nM) * L2E);
        lt = fmaf(l_part[pg * ASPL + s], e, lt);
        od = fmaf(o_part[(size_t)(pg * ASPL + s) * DD + d], e, od);
    }

    const int pair = pg >> 2, g = pg & 3;
    const int h = pair >> 5, b = pair & 31;
    attn_out[(size_t)b * HH + (h * GG + g) * DD + d] = od / fmaxf(lt, 1e-30f);
}

// ---------------- Kernel 5: dense output projection, K-split partials ----------------
__global__ __launch_bounds__(256) void gemm_dense(const float* __restrict__ x,
                                                  const float* __restrict__ wo,
                                                  float* __restrict__ part) {
    const int t = threadIdx.x;
    const int lane_n = t & 63;
    const int bq = t >> 6;
    const int ng = blockIdx.x * 64 + lane_n;
    const int k0 = blockIdx.y * 512;

    float acc[8] = {0.f, 0.f, 0.f, 0.f, 0.f, 0.f, 0.f, 0.f};
    gemm_core(x, wo, HH, ng, k0, bq, acc);

#pragma unroll
    for (int b = 0; b < 8; ++b)
        part[((size_t)blockIdx.y * BB + bq * 8 + b) * HH + ng] = acc[b];
}

// ---------------- Kernel 6: reduce dense partials -> d_out ----------------
__global__ __launch_bounds__(256) void reduce_dense(const float* __restrict__ part,
                                                    float* __restrict__ out) {
    const int idx = blockIdx.x * 256 + threadIdx.x;  // < 32*4096
    float a = 0.f;
#pragma unroll
    for (int s = 0; s < KSPL; ++s) a += part[(size_t)s * (BB * HH) + idx];
    out[idx] = a;
}

extern "C" void kernel_launch(void* const* d_in, const int* in_sizes, int n_in,
                              void* d_out, int out_size, void* d_ws, size_t ws_size,
                              hipStream_t stream) {
    const float* x       = (const float*)d_in[0];
    const float* wq      = (const float*)d_in[1];
    const float* wk      = (const float*)d_in[2];
    const float* wv      = (const float*)d_in[3];
    const float* wo      = (const float*)d_in[4];
    const float* rot     = (const float*)d_in[5];
    const float* cache_k = (const float*)d_in[6];
    const float* cache_v = (const float*)d_in[7];
    const int*   spp     = (const int*)d_in[8];
    const int*   cpp     = (const int*)d_in[9];
    float* out = (float*)d_out;
    float* ws  = (float*)d_ws;

    // workspace layout (floats)
    float* part_qkv = ws;                       // 8*32*6144   = 1,572,864
    float* q_rot    = part_qkv + 1572864;       // 8*32*4*128  =   131,072
    float* k_new    = q_rot + 131072;           // 8*32*128    =    32,768
    float* v_new    = k_new + 32768;            //             =    32,768
    float* m_part   = v_new + 32768;            // 256*4*8     =     8,192
    float* l_part   = m_part + 8192;            //             =     8,192
    float* o_part   = l_part + 8192;            // 256*4*8*128 = 1,048,576
    float* attn_out = o_part + 1048576;         // 32*4096     =   131,072
    float* part_d   = attn_out + 131072;        // 8*32*4096   = 1,048,576

    gemm_qkv<<<dim3(96, KSPL), 256, 0, stream>>>(x, wq, wk, wv, part_qkv);
    rot_kernel<<<1536, 128, 0, stream>>>(part_qkv, rot, q_rot, k_new, v_new);
    attn_kernel<<<dim3(256, ASPL), 256, 0, stream>>>(q_rot, k_new, v_new,
                                                     cache_k, cache_v, spp, cpp,
                                                     m_part, l_part, o_part);
    attn_reduce<<<512, 256, 0, stream>>>(m_part, l_part, o_part, attn_out);
    gemm_dense<<<dim3(64, KSPL), 256, 0, stream>>>(attn_out, wo, part_d);
    reduce_dense<<<512, 256, 0, stream>>>(part_d, out);
}